// Round 2
// baseline (210.803 us; speedup 1.0000x reference)
//
#include <hip/hip_runtime.h>
#include <hip/hip_cooperative_groups.h>
#include <math.h>

namespace cg = cooperative_groups;

#define IN_F   768
#define OUT_F  256
#define NROWS  8192
#define LALPHA 0.2f
#define NBLK   256
#define RPB    32          // rows per block = 8192/256

// ---- workspace layout (floats) ----
// w1[768] @0, w2[768] @768, s1[8192] @1536, s2[8192] @9728, r[8192] @17920, acc768[768] @26112

__device__ inline float waveReduceSum(float v) {
    for (int off = 32; off > 0; off >>= 1) v += __shfl_down(v, off, 64);
    return v;
}
__device__ inline float waveReduceMax(float v) {
    for (int off = 32; off > 0; off >>= 1) v = fmaxf(v, __shfl_down(v, off, 64));
    return v;
}

__global__ void __launch_bounds__(256, 1)
fused_kernel(const float* __restrict__ X, const float* __restrict__ W,
             const float* __restrict__ a,
             float* __restrict__ w1, float* __restrict__ w2,
             float* __restrict__ s1, float* __restrict__ s2,
             float* __restrict__ r,  float* __restrict__ acc768,
             float* __restrict__ out) {
    cg::grid_group grid = cg::this_grid();

    __shared__ float buf[NROWS];        // 32 KB: s2 in ph3, r in ph4/5, reduce scratch in ph6
    __shared__ float wbuf[2 * IN_F];    // 6 KB: 'a' in ph1, w1|w2 in ph2
    __shared__ float part[RPB][9];      // ph3 partial relu-sums (pad 9 -> conflict-free)
    __shared__ float red[8];            // per-wave reduction scratch
    __shared__ float evals[RPB];        // ph5 per-row exp values

    const int tid  = threadIdx.x;
    const int bi   = blockIdx.x;
    const int wid  = tid >> 6;
    const int lane = tid & 63;

    // ---------------- Phase 1: w1 = W@a1, w2 = W@a2 (blocks 0-2); zero acc768 (block 3)
    if (bi < 3) {
        wbuf[tid]       = a[tid];
        wbuf[256 + tid] = a[256 + tid];
        __syncthreads();
        int k = bi * 256 + tid;                      // k in [0,768)
        const float4* rowv = (const float4*)(W + (size_t)k * OUT_F);
        float acc1 = 0.f, acc2 = 0.f;
#pragma unroll 8
        for (int f4 = 0; f4 < OUT_F / 4; ++f4) {
            float4 w = rowv[f4];
            int f = f4 * 4;
            acc1 += w.x * wbuf[f]       + w.y * wbuf[f + 1]       + w.z * wbuf[f + 2]       + w.w * wbuf[f + 3];
            acc2 += w.x * wbuf[256 + f] + w.y * wbuf[256 + f + 1] + w.z * wbuf[256 + f + 2] + w.w * wbuf[256 + f + 3];
        }
        w1[k] = acc1;
        w2[k] = acc2;
    } else if (bi == 3) {
        if (tid < 192) {                             // 192 * 4 = 768 floats
            float4 z = make_float4(0.f, 0.f, 0.f, 0.f);
            ((float4*)acc768)[tid] = z;
        }
    }
    grid.sync();

    // ---------------- Phase 2: s1[i]=X[i]·w1, s2[i]=X[i]·w2 ; block handles rows [32bi,32bi+32)
    wbuf[tid]        = w1[tid];
    wbuf[256 + tid]  = w1[256 + tid];
    wbuf[512 + tid]  = w1[512 + tid];
    wbuf[768 + tid]  = w2[tid];
    wbuf[1024 + tid] = w2[256 + tid];
    wbuf[1280 + tid] = w2[512 + tid];
    __syncthreads();
    {
        const float4* l1 = (const float4*)wbuf;              // 192 float4
        const float4* l2 = (const float4*)(wbuf + IN_F);
        int row0 = bi * RPB + wid * 8;                       // each wave: 8 rows, in pairs
        for (int rp = 0; rp < 8; rp += 2) {
            int rA = row0 + rp, rB = row0 + rp + 1;
            const float4* ra = (const float4*)(X + (size_t)rA * IN_F);
            const float4* rb = (const float4*)(X + (size_t)rB * IN_F);
            float a1 = 0.f, a2 = 0.f, b1 = 0.f, b2 = 0.f;
            for (int c = lane; c < IN_F / 4; c += 64) {      // 3 iters; 6 loads in flight/wave
                float4 xa = ra[c], xb = rb[c];
                float4 u = l1[c], v = l2[c];
                a1 += xa.x * u.x + xa.y * u.y + xa.z * u.z + xa.w * u.w;
                a2 += xa.x * v.x + xa.y * v.y + xa.z * v.z + xa.w * v.w;
                b1 += xb.x * u.x + xb.y * u.y + xb.z * u.z + xb.w * u.w;
                b2 += xb.x * v.x + xb.y * v.y + xb.z * v.z + xb.w * v.w;
            }
            a1 = waveReduceSum(a1); a2 = waveReduceSum(a2);
            b1 = waveReduceSum(b1); b2 = waveReduceSum(b2);
            if (lane == 0) { s1[rA] = a1; s2[rA] = a2; s1[rB] = b1; s2[rB] = b2; }
        }
    }
    grid.sync();

    // ---------------- Phase 3: r[i] = sum_j leakyrelu(s1_i + s2_j), no atomics
    {
        // stage s2 -> buf, accumulate block-wide S_total
        float lsum = 0.f;
#pragma unroll
        for (int p = 0; p < 8; ++p) {
            float4 v = ((const float4*)s2)[tid + p * 256];
            ((float4*)buf)[tid + p * 256] = v;
            lsum += v.x + v.y + v.z + v.w;
        }
        lsum = waveReduceSum(lsum);
        if (lane == 0) red[wid] = lsum;
        __syncthreads();
        float S_total = red[0] + red[1] + red[2] + red[3];

        int ioff  = tid & 31;
        int chunk = tid >> 5;                        // 8 j-chunks of 1024
        int i = bi * RPB + ioff;
        float s1i = s1[i];
        float accp = 0.f;
        const float4* b4 = (const float4*)buf + chunk * 256;
#pragma unroll 8
        for (int j4 = 0; j4 < 256; ++j4) {
            float4 u = b4[j4];                       // <=2 distinct addrs/wave -> free
            accp += fmaxf(s1i + u.x, 0.f);
            accp += fmaxf(s1i + u.y, 0.f);
            accp += fmaxf(s1i + u.z, 0.f);
            accp += fmaxf(s1i + u.w, 0.f);
        }
        part[ioff][chunk] = accp;
        __syncthreads();
        if (tid < 32) {
            float t = 0.f;
#pragma unroll
            for (int c = 0; c < 8; ++c) t += part[tid][c];
            r[bi * RPB + tid] = LALPHA * (8192.f * s1i + S_total) + (1.f - LALPHA) * t;
        }
    }
    grid.sync();

    // ---------------- Phase 4: softmax stats (M, Z) redundantly per block; r -> buf
    float M, Z;
    {
        float4 rv[8];
        float lmax = -INFINITY;
#pragma unroll
        for (int p = 0; p < 8; ++p) {
            rv[p] = ((const float4*)r)[tid + p * 256];
            ((float4*)buf)[tid + p * 256] = rv[p];
            lmax = fmaxf(lmax, fmaxf(fmaxf(rv[p].x, rv[p].y), fmaxf(rv[p].z, rv[p].w)));
        }
        lmax = waveReduceMax(lmax);
        if (lane == 0) red[wid] = lmax;
        __syncthreads();
        M = fmaxf(fmaxf(red[0], red[1]), fmaxf(red[2], red[3]));
        __syncthreads();                             // everyone read red before reuse
        float lz = 0.f;
#pragma unroll
        for (int p = 0; p < 8; ++p) {
            lz += expf(rv[p].x - M) + expf(rv[p].y - M) + expf(rv[p].z - M) + expf(rv[p].w - M);
        }
        lz = waveReduceSum(lz);
        if (lane == 0) red[wid] = lz;
        __syncthreads();
        Z = red[0] + red[1] + red[2] + red[3];
    }

    // ---------------- Phase 5: acc768 += sum_i e_i * X[i]  (skip exp-underflowed rows)
    {
        if (wid == 0) {
            float e = 0.f;
            if (lane < RPB) {
                float ri = buf[bi * RPB + lane];     // full r lives in buf
                e = expf(ri - M);
                evals[lane] = e;
            }
            unsigned long long m = __ballot(e != 0.0f);
            if (lane == 0) red[4] = (m != 0ull) ? 1.0f : 0.0f;
        }
        __syncthreads();
        if (red[4] != 0.0f) {
            float a0 = 0.f, a1 = 0.f, a2 = 0.f;
            for (int k = 0; k < RPB; ++k) {
                float e = evals[k];
                if (e != 0.0f) {
                    const float* row = X + (size_t)(bi * RPB + k) * IN_F;
                    a0 += e * row[tid];
                    a1 += e * row[tid + 256];
                    a2 += e * row[tid + 512];
                }
            }
            atomicAdd(&acc768[tid],       a0);
            atomicAdd(&acc768[tid + 256], a1);
            atomicAdd(&acc768[tid + 512], a2);
        }
    }
    grid.sync();

    // ---------------- Phase 6: out[f] = elu( (acc768 · W[:,f]) / Z ), blocks 0-3
    if (bi < 4) {
        int f  = bi * 64 + lane;                     // output column
        int k0 = wid * 192;                          // k-chunk per wave
        float sum = 0.f;
        for (int k = k0; k < k0 + 192; ++k)
            sum += acc768[k] * W[(size_t)k * OUT_F + f];   // acc768 broadcast, W coalesced
        buf[wid * 64 + lane] = sum;
        __syncthreads();
        if (wid == 0) {
            float tot = buf[lane] + buf[64 + lane] + buf[128 + lane] + buf[192 + lane];
            float x = tot / Z;
            out[bi * 64 + lane] = (x > 0.f) ? x : (expf(x) - 1.0f);
        }
    }
}

extern "C" void kernel_launch(void* const* d_in, const int* in_sizes, int n_in,
                              void* d_out, int out_size, void* d_ws, size_t ws_size,
                              hipStream_t stream) {
    const float* X = (const float*)d_in[0];   // [8192, 768]
    const float* W = (const float*)d_in[1];   // [768, 256]
    const float* a = (const float*)d_in[2];   // [512, 1]
    float* out = (float*)d_out;               // [256]

    float* ws     = (float*)d_ws;
    float* w1     = ws;            // 768
    float* w2     = ws + 768;      // 768
    float* s1     = ws + 1536;     // 8192
    float* s2     = ws + 9728;     // 8192
    float* r      = ws + 17920;    // 8192
    float* acc768 = ws + 26112;    // 768

    void* args[] = { (void*)&X, (void*)&W, (void*)&a,
                     (void*)&w1, (void*)&w2, (void*)&s1, (void*)&s2,
                     (void*)&r, (void*)&acc768, (void*)&out };
    hipLaunchCooperativeKernel((const void*)fused_kernel,
                               dim3(NBLK), dim3(256), args, 0, stream);
}

// Round 3
// 82.226 us; speedup vs baseline: 2.5637x; 2.5637x over previous
//
#include <hip/hip_runtime.h>
#include <math.h>

#define IN_F   768
#define OUT_F  256
#define NROWS  8192
#define LALPHA 0.2f
// Rows with s1max - s1_i > CUT/(alpha*N) have softmax weight < exp(-CUT): droppable.
// Proof: r is monotone increasing in s1 (dr/ds1 = alpha*N + (1-alpha)*count_pos >= alpha*N),
// and r_i - r_max <= alpha*N*(s1_i - s1max) since f(s1_i) <= f(s1max).
#define CUT    60.0f
#define GAP    (CUT / (LALPHA * 8192.0f))   // 0.0366211

// ---- workspace layout (floats): w1[768]@0, w2[768]@768, s1[8192]@1536, s2[8192]@9728

__device__ inline float waveReduceSum(float v) {
    for (int off = 32; off > 0; off >>= 1) v += __shfl_down(v, off, 64);
    return v;
}
__device__ inline float waveReduceMax(float v) {
    for (int off = 32; off > 0; off >>= 1) v = fmaxf(v, __shfl_down(v, off, 64));
    return v;
}
// All 256 threads must call; returns full result to all threads.
__device__ inline float blockReduceSum256(float v, float* red, int tid) {
    v = waveReduceSum(v);
    if ((tid & 63) == 0) red[tid >> 6] = v;
    __syncthreads();
    float r = (red[0] + red[1]) + (red[2] + red[3]);
    __syncthreads();
    return r;
}
__device__ inline float blockReduceMax256(float v, float* red, int tid) {
    v = waveReduceMax(v);
    if ((tid & 63) == 0) red[tid >> 6] = v;
    __syncthreads();
    float r = fmaxf(fmaxf(red[0], red[1]), fmaxf(red[2], red[3]));
    __syncthreads();
    return r;
}

// K0: w1 = W @ a[:256], w2 = W @ a[256:].  grid=96, block=256.
// Each block: 8 k-rows; 32 threads per row read 128B-contiguous chunks (coalesced).
__global__ __launch_bounds__(256) void wvec_kernel(const float* __restrict__ W,
                                                   const float* __restrict__ a,
                                                   float* __restrict__ w1,
                                                   float* __restrict__ w2) {
    __shared__ float la[2 * OUT_F];
    int tid = threadIdx.x;
    la[tid]       = a[tid];
    la[256 + tid] = a[256 + tid];
    __syncthreads();
    int half = tid >> 5;                 // 0..7 : row within block
    int sub  = tid & 31;
    int k = blockIdx.x * 8 + half;       // k in [0,768)
    const float* row = W + (size_t)k * OUT_F;
    float acc1 = 0.f, acc2 = 0.f;
#pragma unroll
    for (int j = 0; j < 8; ++j) {
        int f = sub + 32 * j;
        float w = row[f];
        acc1 += w * la[f];
        acc2 += w * la[256 + f];
    }
    for (int off = 16; off > 0; off >>= 1) {
        acc1 += __shfl_down(acc1, off, 32);
        acc2 += __shfl_down(acc2, off, 32);
    }
    if (sub == 0) { w1[k] = acc1; w2[k] = acc2; }
}

// K1: s1[i] = X[i]·w1, s2[i] = X[i]·w2.  One wave per row. grid=2048, block=256.
// 8 blocks/CU -> 32 waves/CU (max occupancy) to hide HBM latency; BW-bound ~4us.
__global__ __launch_bounds__(256) void s1s2_kernel(const float* __restrict__ X,
                                                   const float* __restrict__ w1,
                                                   const float* __restrict__ w2,
                                                   float* __restrict__ s1,
                                                   float* __restrict__ s2) {
    __shared__ float lw[IN_F * 2];
    int tid = threadIdx.x;
    for (int p = tid; p < IN_F; p += 256) { lw[p] = w1[p]; lw[IN_F + p] = w2[p]; }
    __syncthreads();
    int wid = tid >> 6, lane = tid & 63;
    int i = blockIdx.x * 4 + wid;              // i in [0,8192)
    const float4* row = (const float4*)(X + (size_t)i * IN_F);
    const float4* l1  = (const float4*)lw;
    const float4* l2  = (const float4*)(lw + IN_F);
    float a1 = 0.f, a2 = 0.f;
    for (int c = lane; c < IN_F / 4; c += 64) { // 3 iterations
        float4 x = row[c];
        float4 u = l1[c];
        float4 v = l2[c];
        a1 += x.x * u.x + x.y * u.y + x.z * u.z + x.w * u.w;
        a2 += x.x * v.x + x.y * v.y + x.z * v.z + x.w * v.w;
    }
    a1 = waveReduceSum(a1);
    a2 = waveReduceSum(a2);
    if (lane == 0) { s1[i] = a1; s2[i] = a2; }
}

// K2: everything else, redundantly per block; block b writes out[b].
// grid=256, block=256. Candidate set (rows within GAP of s1max) is ~1-3 rows;
// each candidate's exact r comes from the closed form
//   r_c = alpha*(N*s1_c + S_total) + (1-alpha)*sum_j max(s1_c + s2_j, 0).
__global__ __launch_bounds__(256) void finale_kernel(const float* __restrict__ X,
                                                     const float* __restrict__ W,
                                                     const float* __restrict__ s1g,
                                                     const float* __restrict__ s2g,
                                                     float* __restrict__ out) {
    __shared__ float s1[NROWS];        // 32 KB
    __shared__ float s2[NROWS];        // 32 KB
    __shared__ float y[IN_F];          // 3 KB
    __shared__ float red[4];
    __shared__ int   list[256];
    __shared__ float rlist[256];
    __shared__ int   cnt;
    __shared__ float bc[2];            // {M, Z}
    int tid = threadIdx.x;
    if (tid == 0) cnt = 0;

    // stage s1,s2 into LDS; local max(s1), sum(s2)
    float lmax = -INFINITY, lsum = 0.f;
#pragma unroll
    for (int p = 0; p < 8; ++p) {
        float4 v1 = ((const float4*)s1g)[tid + 256 * p];
        float4 v2 = ((const float4*)s2g)[tid + 256 * p];
        ((float4*)s1)[tid + 256 * p] = v1;
        ((float4*)s2)[tid + 256 * p] = v2;
        lmax = fmaxf(lmax, fmaxf(fmaxf(v1.x, v1.y), fmaxf(v1.z, v1.w)));
        lsum += (v2.x + v2.y) + (v2.z + v2.w);
    }
    __syncthreads();                    // LDS staging complete (also before red use)
    float s1max   = blockReduceMax256(lmax, red, tid);
    float S_total = blockReduceSum256(lsum, red, tid);

    // candidate scan
    float thr = s1max - GAP;
    for (int i = tid; i < NROWS; i += 256) {
        if (s1[i] >= thr) {
            int p = atomicAdd(&cnt, 1);
            if (p < 256) list[p] = i;
        }
    }
    __syncthreads();
    int n = cnt < 256 ? cnt : 256;
    if (tid == 0) {                     // deterministic order: sort tiny list by index
        for (int i = 1; i < n; ++i) {
            int key = list[i], j = i - 1;
            while (j >= 0 && list[j] > key) { list[j + 1] = list[j]; --j; }
            list[j + 1] = key;
        }
    }
    __syncthreads();

    // exact r for each candidate
    for (int c = 0; c < n; ++c) {
        float s1c = s1[list[c]];
        float acc = 0.f;
#pragma unroll
        for (int p = 0; p < 8; ++p) {
            float4 v = ((const float4*)s2)[tid + 256 * p];
            acc += fmaxf(s1c + v.x, 0.f) + fmaxf(s1c + v.y, 0.f)
                 + fmaxf(s1c + v.z, 0.f) + fmaxf(s1c + v.w, 0.f);
        }
        float f_c = blockReduceSum256(acc, red, tid);
        if (tid == 0)
            rlist[c] = LALPHA * (8192.f * s1c + S_total) + (1.f - LALPHA) * f_c;
    }
    __syncthreads();

    // softmax over candidates (skipped rows underflow exactly)
    if (tid == 0) {
        float M = -INFINITY;
        for (int c = 0; c < n; ++c) M = fmaxf(M, rlist[c]);
        float Z = 0.f;
        for (int c = 0; c < n; ++c) { float e = expf(rlist[c] - M); rlist[c] = e; Z += e; }
        bc[0] = M; bc[1] = Z;
    }
    __syncthreads();
    float invZ = 1.0f / bc[1];

    // y = sum_c (e_c/Z) * X[idx_c]
    for (int p = tid; p < IN_F; p += 256) {
        float acc = 0.f;
        for (int c = 0; c < n; ++c)
            acc += rlist[c] * X[(size_t)list[c] * IN_F + p];
        y[p] = acc * invZ;
    }
    __syncthreads();

    // out[b] = elu( y · W[:, b] )
    int b = blockIdx.x;
    float part = y[tid]       * W[(size_t)tid * OUT_F + b]
               + y[tid + 256] * W[(size_t)(tid + 256) * OUT_F + b]
               + y[tid + 512] * W[(size_t)(tid + 512) * OUT_F + b];
    float tot = blockReduceSum256(part, red, tid);
    if (tid == 0) out[b] = (tot > 0.f) ? tot : (expf(tot) - 1.0f);
}

extern "C" void kernel_launch(void* const* d_in, const int* in_sizes, int n_in,
                              void* d_out, int out_size, void* d_ws, size_t ws_size,
                              hipStream_t stream) {
    const float* X = (const float*)d_in[0];   // [8192, 768]
    const float* W = (const float*)d_in[1];   // [768, 256]
    const float* a = (const float*)d_in[2];   // [512, 1]
    float* out = (float*)d_out;               // [256]

    float* ws = (float*)d_ws;
    float* w1 = ws;            // 768
    float* w2 = ws + 768;      // 768
    float* s1 = ws + 1536;     // 8192
    float* s2 = ws + 9728;     // 8192

    wvec_kernel<<<96, 256, 0, stream>>>(W, a, w1, w2);
    s1s2_kernel<<<2048, 256, 0, stream>>>(X, w1, w2, s1, s2);
    finale_kernel<<<256, 256, 0, stream>>>(X, W, s1, s2, out);
}

// Round 4
// 80.633 us; speedup vs baseline: 2.6144x; 1.0198x over previous
//
#include <hip/hip_runtime.h>
#include <math.h>

#define IN_F   768
#define OUT_F  256
#define NROWS  8192
#define LALPHA 0.2f
// Rows with s1max - s1_i > CUT/(alpha*N) have softmax weight < exp(-CUT): droppable.
// r is monotone increasing in s1 (dr/ds1 >= alpha*N) and r_i - r_max <= alpha*N*(s1_i - s1max).
#define CUT    60.0f
#define GAP    (CUT / (LALPHA * 8192.0f))   // 0.0366211
#define MAXC   64

// ---- workspace layout (floats): w1[768]@0, w2[768]@768, s1[8192]@1536, s2[8192]@9728

__device__ inline float waveReduceSum(float v) {
    for (int off = 32; off > 0; off >>= 1) v += __shfl_down(v, off, 64);
    return v;
}
__device__ inline float waveReduceMax(float v) {
    for (int off = 32; off > 0; off >>= 1) v = fmaxf(v, __shfl_down(v, off, 64));
    return v;
}
__device__ inline float blockReduceMax256(float v, float* red, int tid) {
    v = waveReduceMax(v);
    if ((tid & 63) == 0) red[tid >> 6] = v;
    __syncthreads();
    float r = fmaxf(fmaxf(red[0], red[1]), fmaxf(red[2], red[3]));
    __syncthreads();
    return r;
}

// K0: w1 = W @ a[:256], w2 = W @ a[256:].  grid=96, block=256.
__global__ __launch_bounds__(256) void wvec_kernel(const float* __restrict__ W,
                                                   const float* __restrict__ a,
                                                   float* __restrict__ w1,
                                                   float* __restrict__ w2) {
    __shared__ float la[2 * OUT_F];
    int tid = threadIdx.x;
    la[tid]       = a[tid];
    la[256 + tid] = a[256 + tid];
    __syncthreads();
    int half = tid >> 5;                 // 0..7 : row within block
    int sub  = tid & 31;
    int k = blockIdx.x * 8 + half;       // k in [0,768)
    const float* row = W + (size_t)k * OUT_F;
    float acc1 = 0.f, acc2 = 0.f;
#pragma unroll
    for (int j = 0; j < 8; ++j) {
        int f = sub + 32 * j;
        float w = row[f];
        acc1 += w * la[f];
        acc2 += w * la[256 + f];
    }
    for (int off = 16; off > 0; off >>= 1) {
        acc1 += __shfl_down(acc1, off, 32);
        acc2 += __shfl_down(acc2, off, 32);
    }
    if (sub == 0) { w1[k] = acc1; w2[k] = acc2; }
}

// K1: s1[i] = X[i]·w1, s2[i] = X[i]·w2.  One wave per row. grid=2048, block=256.
__global__ __launch_bounds__(256) void s1s2_kernel(const float* __restrict__ X,
                                                   const float* __restrict__ w1,
                                                   const float* __restrict__ w2,
                                                   float* __restrict__ s1,
                                                   float* __restrict__ s2) {
    __shared__ float lw[IN_F * 2];
    int tid = threadIdx.x;
    for (int p = tid; p < IN_F; p += 256) { lw[p] = w1[p]; lw[IN_F + p] = w2[p]; }
    __syncthreads();
    int wid = tid >> 6, lane = tid & 63;
    int i = blockIdx.x * 4 + wid;              // i in [0,8192)
    const float4* row = (const float4*)(X + (size_t)i * IN_F);
    const float4* l1  = (const float4*)lw;
    const float4* l2  = (const float4*)(lw + IN_F);
    float a1 = 0.f, a2 = 0.f;
#pragma unroll
    for (int c0 = 0; c0 < 3; ++c0) {           // 3 independent float4 loads in flight
        int c = lane + 64 * c0;
        float4 x = row[c];
        float4 u = l1[c];
        float4 v = l2[c];
        a1 += x.x * u.x + x.y * u.y + x.z * u.z + x.w * u.w;
        a2 += x.x * v.x + x.y * v.y + x.z * v.z + x.w * v.w;
    }
    a1 = waveReduceSum(a1);
    a2 = waveReduceSum(a2);
    if (lane == 0) { s1[i] = a1; s2[i] = a2; }
}

// K2: candidates + softmax + weighted row + output matvec, redundantly per block.
// grid=64, block=256; block b writes out[4b..4b+4).
__global__ __launch_bounds__(256) void finale_kernel(const float* __restrict__ X,
                                                     const float* __restrict__ W,
                                                     const float* __restrict__ s1g,
                                                     const float* __restrict__ s2g,
                                                     float* __restrict__ out) {
    __shared__ float  s2[NROWS];       // 32 KB
    __shared__ float  y[IN_F];         // 3 KB
    __shared__ float  red[4];
    __shared__ float4 red4[4];
    __shared__ int    list[MAXC];
    __shared__ float  slist[MAXC];     // candidate s1 values
    __shared__ float  rlist[MAXC];     // candidate r (then unused)
    __shared__ float  wts[MAXC];       // normalized softmax weights
    __shared__ int    cnt;
    int tid = threadIdx.x;
    int wid = tid >> 6, lane = tid & 63;
    if (tid == 0) cnt = 0;

    // s1 -> registers (for max + scan), s2 -> LDS
    float4 rv[8];
    float lmax = -INFINITY;
#pragma unroll
    for (int p = 0; p < 8; ++p) {
        rv[p] = ((const float4*)s1g)[tid + 256 * p];
        float4 v2 = ((const float4*)s2g)[tid + 256 * p];
        ((float4*)s2)[tid + 256 * p] = v2;
        lmax = fmaxf(lmax, fmaxf(fmaxf(rv[p].x, rv[p].y), fmaxf(rv[p].z, rv[p].w)));
    }
    // blockReduceMax's internal sync also fences the s2 staging + cnt init
    float s1max = blockReduceMax256(lmax, red, tid);
    float thr = s1max - GAP;

    // candidate scan from registers
#pragma unroll
    for (int p = 0; p < 8; ++p) {
        int base = 4 * (tid + 256 * p);
        float v[4] = { rv[p].x, rv[p].y, rv[p].z, rv[p].w };
#pragma unroll
        for (int q = 0; q < 4; ++q) {
            if (v[q] >= thr) {
                int pos = atomicAdd(&cnt, 1);
                if (pos < MAXC) { list[pos] = base + q; slist[pos] = v[q]; }
            }
        }
    }
    __syncthreads();
    int n = cnt < MAXC ? cnt : MAXC;
    if (tid == 0 && n > 1) {           // deterministic order (atomic order varies)
        for (int i = 1; i < n; ++i) {
            int ki = list[i]; float kv = slist[i]; int j = i - 1;
            while (j >= 0 && list[j] > ki) {
                list[j + 1] = list[j]; slist[j + 1] = slist[j]; --j;
            }
            list[j + 1] = ki; slist[j + 1] = kv;
        }
    }
    __syncthreads();

    // exact r per candidate (wave-parallel).  alpha*S_total shift dropped: softmax-invariant.
    if (n > 1) {
        for (int c = wid; c < n; c += 4) {
            float s1c = slist[c];
            float acc = 0.f;
#pragma unroll 4
            for (int q = lane; q < NROWS / 4; q += 64) {   // 32 float4 per lane
                float4 v = ((const float4*)s2)[q];
                acc += fmaxf(s1c + v.x, 0.f) + fmaxf(s1c + v.y, 0.f)
                     + fmaxf(s1c + v.z, 0.f) + fmaxf(s1c + v.w, 0.f);
            }
            acc = waveReduceSum(acc);
            if (lane == 0)
                rlist[c] = LALPHA * 8192.f * s1c + (1.f - LALPHA) * acc;
        }
    }
    __syncthreads();
    if (tid == 0) {
        if (n == 1) wts[0] = 1.0f;
        else {
            float M = -INFINITY;
            for (int c = 0; c < n; ++c) M = fmaxf(M, rlist[c]);
            float Z = 0.f;
            for (int c = 0; c < n; ++c) { float e = expf(rlist[c] - M); rlist[c] = e; Z += e; }
            float invZ = 1.0f / Z;
            for (int c = 0; c < n; ++c) wts[c] = rlist[c] * invZ;
        }
    }
    __syncthreads();

    // y = sum_c wts[c] * X[idx_c]
    for (int p = tid; p < IN_F; p += 256) {
        float acc = 0.f;
        for (int c = 0; c < n; ++c)
            acc += wts[c] * X[(size_t)list[c] * IN_F + p];
        y[p] = acc;
    }
    __syncthreads();

    // out[4b..4b+4) = elu( y · W[:, 4b..4b+4) );  W rows read as float4 (coalesced lines)
    int b4 = blockIdx.x * 4;
    float4 acc = make_float4(0.f, 0.f, 0.f, 0.f);
#pragma unroll
    for (int j = 0; j < 3; ++j) {
        int k = tid + 256 * j;
        float4 w = *(const float4*)(W + (size_t)k * OUT_F + b4);
        float yk = y[k];
        acc.x += yk * w.x; acc.y += yk * w.y; acc.z += yk * w.z; acc.w += yk * w.w;
    }
    for (int off = 32; off > 0; off >>= 1) {
        acc.x += __shfl_down(acc.x, off, 64);
        acc.y += __shfl_down(acc.y, off, 64);
        acc.z += __shfl_down(acc.z, off, 64);
        acc.w += __shfl_down(acc.w, off, 64);
    }
    if (lane == 0) red4[wid] = acc;
    __syncthreads();
    if (tid == 0) {
        float4 t;
        t.x = red4[0].x + red4[1].x + red4[2].x + red4[3].x;
        t.y = red4[0].y + red4[1].y + red4[2].y + red4[3].y;
        t.z = red4[0].z + red4[1].z + red4[2].z + red4[3].z;
        t.w = red4[0].w + red4[1].w + red4[2].w + red4[3].w;
        out[b4 + 0] = (t.x > 0.f) ? t.x : (expf(t.x) - 1.0f);
        out[b4 + 1] = (t.y > 0.f) ? t.y : (expf(t.y) - 1.0f);
        out[b4 + 2] = (t.z > 0.f) ? t.z : (expf(t.z) - 1.0f);
        out[b4 + 3] = (t.w > 0.f) ? t.w : (expf(t.w) - 1.0f);
    }
}

extern "C" void kernel_launch(void* const* d_in, const int* in_sizes, int n_in,
                              void* d_out, int out_size, void* d_ws, size_t ws_size,
                              hipStream_t stream) {
    const float* X = (const float*)d_in[0];   // [8192, 768]
    const float* W = (const float*)d_in[1];   // [768, 256]
    const float* a = (const float*)d_in[2];   // [512, 1]
    float* out = (float*)d_out;               // [256]

    float* ws = (float*)d_ws;
    float* w1 = ws;            // 768
    float* w2 = ws + 768;      // 768
    float* s1 = ws + 1536;     // 8192
    float* s2 = ws + 9728;     // 8192

    wvec_kernel<<<96, 256, 0, stream>>>(W, a, w1, w2);
    s1s2_kernel<<<2048, 256, 0, stream>>>(X, w1, w2, s1, s2);
    finale_kernel<<<64, 256, 0, stream>>>(X, W, s1, s2, out);
}